// Round 2
// baseline (428.460 us; speedup 1.0000x reference)
//
#include <hip/hip_runtime.h>
#include <hip/hip_bf16.h>

// AdaBiD: fused graph-diffusion + encoder/decoder MLP for MI355X (gfx950).
// B=8, T=12, N=1536, H=64, TH=768, HID2=128, T_OUT=12.
// Robust to input dtype (bf16 OR f32): a detector kernel sniffs x's bit
// pattern, a canonicalize kernel converts all inputs to fp32 in ws, and the
// final store branches bf16/f32 on the same flag.
// Pipeline:
//   K0 detect: bf16-vs-f32 sniff on x -> flag in ws
//   K1 canon:  all 25 inputs -> fp32 canonical region in ws
//   K2 prep:   per (b,n): softmax over T, logp, self-dot, xT
//   K3 kl:     per block: 32 i x 8 j-slots, fused kl[i,j]/kl[j,i] threshold +
//              A@x / A^T@x accumulation, shfl_xor reduce, write c directly
//   K4..K9:    MLP GEMMs (fp32 VALU); z (B,N,768) generated on the fly.

namespace {

constexpr int Bn = 8, Tn = 12, Nn = 1536, TOUT = 12;
constexpr int Mrows = Bn * Nn;   // 12288

__device__ __forceinline__ float b2f(const __hip_bfloat16 v) { return __bfloat162float(v); }
__device__ __forceinline__ __hip_bfloat16 f2b(float v) { return __float2bfloat16(v); }

// ---------------- K0: dtype detector ----------------------------------------
// bf16 N(0,1) data: bf16 exponent field <= ~130, never >= 140.
// f32 data read as ushorts: half the samples are mantissa-low-halves with
// ~uniform exponent bits -> ~45% have e >= 140.
__global__ void detect_kernel(const void* __restrict__ x, int* __restrict__ flag) {
  __shared__ int cnt;
  if (threadIdx.x == 0) cnt = 0;
  __syncthreads();
  const unsigned short* u = (const unsigned short*)x;
  int c = 0;
#pragma unroll
  for (int s = 0; s < 16; ++s) {
    unsigned short v = u[threadIdx.x + s * 256];   // 4096 samples, safe in both worlds
    int e = (v >> 7) & 0xFF;
    if (e >= 140) c++;
  }
  atomicAdd(&cnt, c);
  __syncthreads();
  if (threadIdx.x == 0) flag[0] = (cnt > 64) ? 1 : 0;  // 1 = f32 inputs
}

// ---------------- K1: canonicalize all inputs to fp32 ------------------------
struct CanonTab {
  const void* src[25];
  int n[25];
  int off[25];
};

__global__ __launch_bounds__(256) void convert_kernel(
    CanonTab tab, const int* __restrict__ flag, float* __restrict__ canon) {
  int inp = blockIdx.y;
  int idx = blockIdx.x * 256 + threadIdx.x;
  if (idx >= tab.n[inp]) return;
  float v;
  if (flag[0]) v = ((const float*)tab.src[inp])[idx];
  else         v = b2f(((const __hip_bfloat16*)tab.src[inp])[idx]);
  canon[tab.off[inp] + idx] = v;
}

// ---------------- K2: softmax / logp / self-dot / x transpose ----------------
__global__ __launch_bounds__(256) void prep_kernel(
    const float* __restrict__ x,
    float* __restrict__ xT, float* __restrict__ p,
    float* __restrict__ lp, float* __restrict__ sd) {
  int tid = blockIdx.x * 256 + threadIdx.x;
  if (tid >= Mrows) return;
  int b = tid / Nn, n = tid - b * Nn;
  float xv[12];
#pragma unroll
  for (int t = 0; t < 12; ++t)
    xv[t] = x[((size_t)(b * Tn + t)) * Nn + n];
  float mx = xv[0];
#pragma unroll
  for (int t = 1; t < 12; ++t) mx = fmaxf(mx, xv[t]);
  float e[12]; float Z = 0.f;
#pragma unroll
  for (int t = 0; t < 12; ++t) { e[t] = expf(xv[t] - mx); Z += e[t]; }
  float invZ = 1.f / Z;
  float sacc = 0.f;
  size_t base = (size_t)tid * 12;
#pragma unroll
  for (int t = 0; t < 12; ++t) {
    float pv = e[t] * invZ;
    float lv = logf(pv + 1e-10f);
    p[base + t] = pv;
    lp[base + t] = lv;
    xT[base + t] = xv[t];
    sacc += pv * lv;
  }
  sd[tid] = sacc;
}

// ---------------- K3: fused KL threshold + bidirectional aggregation ---------
// block = (b, chunk of 32 i). threads: il = tid>>3 (i), jsl = tid&7 (j slot).
// Each thread covers j = jsl + 8*jj, jj in [0,192). shfl_xor reduce over the
// 8 j-slots (consecutive lanes), jsl==0 writes c directly. No partial buffers.
__global__ __launch_bounds__(256) void kl_kernel(
    const float* __restrict__ p, const float* __restrict__ lp,
    const float* __restrict__ xT, const float* __restrict__ sd,
    float* __restrict__ cc) {
  int blk = blockIdx.x;        // 0..383
  int b  = blk / 48;
  int ic = blk % 48;
  int tid = threadIdx.x;
  int il = tid >> 3;           // 0..31
  int jsl = tid & 7;           // 0..7
  int i = ic * 32 + il;
  int gi = b * Nn + i;

  float pi[12] __attribute__((aligned(16)));
  float li[12] __attribute__((aligned(16)));
  {
    const float4* p4 = (const float4*)(p + (size_t)gi * 12);
    ((float4*)pi)[0] = p4[0]; ((float4*)pi)[1] = p4[1]; ((float4*)pi)[2] = p4[2];
    const float4* l4 = (const float4*)(lp + (size_t)gi * 12);
    ((float4*)li)[0] = l4[0]; ((float4*)li)[1] = l4[1]; ((float4*)li)[2] = l4[2];
  }
  float self_i = sd[gi];

  float sf[12], sb[12];
#pragma unroll
  for (int t = 0; t < 12; ++t) { sf[t] = 0.f; sb[t] = 0.f; }
  float rs = 0.f, cs = 0.f;

  const float* pb  = p  + (size_t)b * Nn * 12;
  const float* lb  = lp + (size_t)b * Nn * 12;
  const float* xb  = xT + (size_t)b * Nn * 12;
  const float* sdb = sd + b * Nn;

  for (int jj = 0; jj < 192; ++jj) {
    int j = jsl + (jj << 3);
    float pj[12] __attribute__((aligned(16)));
    float lj[12] __attribute__((aligned(16)));
    float xj[12] __attribute__((aligned(16)));
    {
      const float4* a = (const float4*)(pb + (size_t)j * 12);
      ((float4*)pj)[0] = a[0]; ((float4*)pj)[1] = a[1]; ((float4*)pj)[2] = a[2];
      const float4* c4 = (const float4*)(lb + (size_t)j * 12);
      ((float4*)lj)[0] = c4[0]; ((float4*)lj)[1] = c4[1]; ((float4*)lj)[2] = c4[2];
      const float4* d4 = (const float4*)(xb + (size_t)j * 12);
      ((float4*)xj)[0] = d4[0]; ((float4*)xj)[1] = d4[1]; ((float4*)xj)[2] = d4[2];
    }
    float self_j = sdb[j];
    float da = 0.f, db = 0.f;
#pragma unroll
    for (int t = 0; t < 12; ++t) {
      da = fmaf(pi[t], lj[t], da);   // kl[i,j] cross term
      db = fmaf(pj[t], li[t], db);   // kl[j,i] cross term
    }
    float cf = ((self_i - da) < 0.5f) ? 1.f : 0.f;  // A[i,j]
    float cb = ((self_j - db) < 0.5f) ? 1.f : 0.f;  // A[j,i]
    rs += cf; cs += cb;
#pragma unroll
    for (int t = 0; t < 12; ++t) {
      sf[t] = fmaf(cf, xj[t], sf[t]);
      sb[t] = fmaf(cb, xj[t], sb[t]);
    }
  }

  // reduce across the 8 j-slots (lanes l, l^1, l^2, l^4 share an i)
#pragma unroll
  for (int off = 1; off <= 4; off <<= 1) {
    rs += __shfl_xor(rs, off);
    cs += __shfl_xor(cs, off);
#pragma unroll
    for (int t = 0; t < 12; ++t) {
      sf[t] += __shfl_xor(sf[t], off);
      sb[t] += __shfl_xor(sb[t], off);
    }
  }

  if (jsl == 0) {
    float irs = 1.f / fmaxf(rs, 1e-6f);
    float ics = 1.f / fmaxf(cs, 1e-6f);
#pragma unroll
    for (int t = 0; t < 12; ++t)
      cc[(size_t)gi * 12 + t] = 3.0f * (0.3f * sf[t] * irs + 0.7f * sb[t] * ics);
  }
}

// ---------------- GEMM: TM=64 x TN tile, KC=32, 256 threads ------------------
// AMODE 0: A is f32 buffer [M x Kw].  AMODE 1: zgen - A element (row,k) is
// relu(xT[row, k/64]*W1[k%64] + c[row, k/64]*W2[k%64]) computed on the fly.
template <int TN, int AMODE>
__device__ __forceinline__ void gemm_pair(
    float (&acc)[4][TN / 16], int row0, int Kw,
    const float* __restrict__ A, const float* __restrict__ W,
    const float* __restrict__ zxT, const float* __restrict__ zc,
    const float* __restrict__ zW1, const float* __restrict__ zW2,
    int Nvalid, float (*As)[65], float* Ws) {
  constexpr int CT = TN / 16;
  const int tid = threadIdx.x;
  const int tx = tid & 15, ty = tid >> 4;
  for (int k0 = 0; k0 < Kw; k0 += 32) {
    __syncthreads();
    // stage A tile: 64 rows x 32 k (k contiguous per row -> coalesced)
#pragma unroll
    for (int s = 0; s < 8; ++s) {
      int flat = tid + s * 256;
      int r = flat >> 5, kk = flat & 31;
      float v;
      if (AMODE == 0) {
        v = A[(size_t)(row0 + r) * Kw + (k0 + kk)];
      } else {
        int k = k0 + kk;
        int t = k >> 6, h = k & 63;
        float xv = zxT[(size_t)(row0 + r) * 12 + t];
        float cv = zc[(size_t)(row0 + r) * 12 + t];
        v = fmaxf(fmaf(xv, zW1[h], cv * zW2[h]), 0.f);
      }
      As[kk][r] = v;
    }
    // stage W tile: 32 k x TN cols
#pragma unroll
    for (int s = 0; s < (32 * TN) / 256; ++s) {
      int flat = tid + s * 256;
      int kk = flat / TN, c = flat - kk * TN;
      float w = 0.f;
      if (TN == 16) {
        if (c < Nvalid) w = W[(size_t)(k0 + kk) * Nvalid + c];
      } else {
        w = W[(size_t)(k0 + kk) * TN + c];
      }
      Ws[kk * TN + c] = w;
    }
    __syncthreads();
#pragma unroll
    for (int kk = 0; kk < 32; ++kk) {
      float a[4];
#pragma unroll
      for (int i = 0; i < 4; ++i) a[i] = As[kk][ty * 4 + i];
      float wv[CT];
#pragma unroll
      for (int u = 0; u < CT; ++u) wv[u] = Ws[kk * TN + tx * CT + u];
#pragma unroll
      for (int i = 0; i < 4; ++i)
#pragma unroll
        for (int u = 0; u < CT; ++u) acc[i][u] = fmaf(a[i], wv[u], acc[i][u]);
    }
  }
}

// EPI 0: relu -> f32 [M x TN]; EPI 1: BN -> f32 [M x TN];
// EPI 2: BN -> transposed final output out[b, c, n] (dtype per flag).
template <int TN, int AM1, int KW1, int AM2, int KW2, int EPI>
__global__ __launch_bounds__(256) void mlp_gemm(
    const float* __restrict__ A1, const float* __restrict__ Wa,
    const float* __restrict__ A2, const float* __restrict__ Wb,
    const float* __restrict__ bias,
    const float* __restrict__ bng, const float* __restrict__ bnbe,
    const float* __restrict__ bnm, const float* __restrict__ bnv,
    const float* __restrict__ zxT, const float* __restrict__ zc,
    const float* __restrict__ zW1, const float* __restrict__ zW2,
    void* __restrict__ outp, int Nvalid, const int* __restrict__ flag) {
  __shared__ float As[32][65];
  __shared__ float Ws[32 * TN];
  constexpr int CT = TN / 16;
  float acc[4][CT];
#pragma unroll
  for (int i = 0; i < 4; ++i)
#pragma unroll
    for (int u = 0; u < CT; ++u) acc[i][u] = 0.f;
  const int row0 = blockIdx.x * 64;
  gemm_pair<TN, AM1>(acc, row0, KW1, A1, Wa, zxT, zc, zW1, zW2, Nvalid, As, Ws);
  if constexpr (KW2 > 0)
    gemm_pair<TN, AM2>(acc, row0, KW2, A2, Wb, zxT, zc, zW1, zW2, Nvalid, As, Ws);

  const int tid = threadIdx.x;
  const int tx = tid & 15, ty = tid >> 4;
  int isf32 = (EPI == 2) ? flag[0] : 0;
#pragma unroll
  for (int u = 0; u < CT; ++u) {
    int c = tx * CT + u;
    bool valid = (TN == 16) ? (c < Nvalid) : true;
    float bz = valid ? bias[c] : 0.f;
    float scale = 1.f, shift = 0.f;
    if (EPI >= 1 && valid) {
      float g = bng[c], be = bnbe[c], m = bnm[c], v = bnv[c];
      scale = g / sqrtf(v + 1e-5f);
      shift = be - m * scale;
    }
#pragma unroll
    for (int i = 0; i < 4; ++i) {
      int row = row0 + ty * 4 + i;
      float val = acc[i][u] + bz;
      if (EPI == 0) {
        ((float*)outp)[(size_t)row * TN + c] = fmaxf(val, 0.f);
      } else if (EPI == 1) {
        ((float*)outp)[(size_t)row * TN + c] = val * scale + shift;
      } else {
        if (valid) {
          int bb = row / Nn, nn = row - bb * Nn;
          size_t oidx = ((size_t)bb * TOUT + c) * Nn + nn;
          float vv = val * scale + shift;
          if (isf32) ((float*)outp)[oidx] = vv;
          else       ((__hip_bfloat16*)outp)[oidx] = f2b(vv);
        }
      }
    }
  }
}

// canonical fp32 layout offsets (relative to canon base), dict order
static const int kOff[25] = {
    0, 147456, 147520, 147584, 245888, 246016, 262400, 262528, 270720, 270784,
    319936, 320000, 320064, 320128, 320192, 328384, 328512, 344896, 345024,
    346560, 346572, 347340, 347352, 347364, 347376};
static const int kN[25] = {
    147456, 64, 64, 98304, 128, 16384, 128, 8192, 64, 49152,
    64, 64, 64, 64, 8192, 128, 16384, 128, 1536,
    12, 768, 12, 12, 12, 12};

}  // namespace

extern "C" void kernel_launch(void* const* d_in, const int* in_sizes, int n_in,
                              void* d_out, int out_size, void* d_ws, size_t ws_size,
                              hipStream_t stream) {
  float* f = (float*)d_ws;
  int* flag = (int*)d_ws;            // f[0..3]
  float* CB = f + 16;                // canonical fp32 inputs, 347388 floats
  // scratch after canon (16B-aligned starts)
  float* xT = f + 347408;            // 147456
  float* p  = f + 494864;            // 147456
  float* lp = f + 642320;            // 147456
  float* sd = f + 789776;            // 12288
  float* cc = f + 802064;            // 147456
  float* bufA = f + 949520;          // 12288*128
  float* bufB = f + 2522384;         // 12288*128
  float* xe   = f + 4095248;         // 12288*64   (ends 4881680 -> 19.5 MB)

  CanonTab tab;
  for (int i = 0; i < 25; ++i) { tab.src[i] = d_in[i]; tab.n[i] = kN[i]; tab.off[i] = kOff[i]; }

  const float* cx   = CB + kOff[0];
  const float* cW1  = CB + kOff[1];
  const float* cW2  = CB + kOff[2];
  const float* cew1 = CB + kOff[3];
  const float* ceb1 = CB + kOff[4];
  const float* cew2 = CB + kOff[5];
  const float* ceb2 = CB + kOff[6];
  const float* cew3 = CB + kOff[7];
  const float* ceb3 = CB + kOff[8];
  const float* cepj = CB + kOff[9];
  const float* cebg = CB + kOff[10];
  const float* cebb = CB + kOff[11];
  const float* cebm = CB + kOff[12];
  const float* cebv = CB + kOff[13];
  const float* cdw1 = CB + kOff[14];
  const float* cdb1 = CB + kOff[15];
  const float* cdw2 = CB + kOff[16];
  const float* cdb2 = CB + kOff[17];
  const float* cdw3 = CB + kOff[18];
  const float* cdb3 = CB + kOff[19];
  const float* cdpj = CB + kOff[20];
  const float* cdbg = CB + kOff[21];
  const float* cdbb = CB + kOff[22];
  const float* cdbm = CB + kOff[23];
  const float* cdbv = CB + kOff[24];

  detect_kernel<<<1, 256, 0, stream>>>(d_in[0], flag);
  convert_kernel<<<dim3(576, 25), 256, 0, stream>>>(tab, flag, CB);
  prep_kernel<<<48, 256, 0, stream>>>(cx, xT, p, lp, sd);
  kl_kernel<<<384, 256, 0, stream>>>(p, lp, xT, sd, cc);

  const int G = Mrows / 64;  // 192
  // L1e: bufA = relu(z @ enc_w1 + b1), z generated on the fly (K=768)
  mlp_gemm<128, 1, 768, 0, 0, 0><<<G, 256, 0, stream>>>(
      nullptr, cew1, nullptr, nullptr, ceb1,
      nullptr, nullptr, nullptr, nullptr, xT, cc, cW1, cW2, bufA, 128, flag);
  // L2e: bufB = relu(bufA @ enc_w2 + b2)
  mlp_gemm<128, 0, 128, 0, 0, 0><<<G, 256, 0, stream>>>(
      bufA, cew2, nullptr, nullptr, ceb2,
      nullptr, nullptr, nullptr, nullptr, nullptr, nullptr, nullptr, nullptr, bufB, 128, flag);
  // L3e: xe = BN(bufB @ enc_w3 + b3 + z @ enc_proj)
  mlp_gemm<64, 0, 128, 1, 768, 1><<<G, 256, 0, stream>>>(
      bufB, cew3, nullptr, cepj, ceb3,
      cebg, cebb, cebm, cebv, xT, cc, cW1, cW2, xe, 64, flag);
  // L1d: bufA = relu(xe @ dec_w1 + b1)
  mlp_gemm<128, 0, 64, 0, 0, 0><<<G, 256, 0, stream>>>(
      xe, cdw1, nullptr, nullptr, cdb1,
      nullptr, nullptr, nullptr, nullptr, nullptr, nullptr, nullptr, nullptr, bufA, 128, flag);
  // L2d: bufB = relu(bufA @ dec_w2 + b2)
  mlp_gemm<128, 0, 128, 0, 0, 0><<<G, 256, 0, stream>>>(
      bufA, cdw2, nullptr, nullptr, cdb2,
      nullptr, nullptr, nullptr, nullptr, nullptr, nullptr, nullptr, nullptr, bufB, 128, flag);
  // L3d: out[b,t,n] = BN(bufB @ dec_w3 + b3 + xe @ dec_proj)[b,n,t]
  mlp_gemm<16, 0, 128, 0, 64, 2><<<G, 256, 0, stream>>>(
      bufB, cdw3, xe, cdpj, cdb3,
      cdbg, cdbb, cdbm, cdbv, nullptr, nullptr, nullptr, nullptr, d_out, 12, flag);
}

// Round 3
// 258.056 us; speedup vs baseline: 1.6603x; 1.6603x over previous
//
#include <hip/hip_runtime.h>
#include <hip/hip_bf16.h>

// AdaBiD: fused graph-diffusion + encoder/decoder MLP for MI355X (gfx950).
// B=8, T=12, N=1536, H=64, TH=768, HID2=128, T_OUT=12.
// R3: kl 4-way j-split (occupancy 1.5->6 waves/SIMD) + MLP chain on bf16 MFMA
// (16x16x32) with weights pre-repacked into B-fragment order -> no LDS, no
// barriers in the GEMMs; A-frags loaded (or z-generated) straight to VGPRs.

namespace {

constexpr int Bn = 8, Tn = 12, Nn = 1536, TOUT = 12;
constexpr int Mrows = Bn * Nn;   // 12288

typedef __attribute__((ext_vector_type(8))) short bf8;
typedef __attribute__((ext_vector_type(4))) float f4;

__device__ __forceinline__ float b2f(const __hip_bfloat16 v) { return __bfloat162float(v); }
__device__ __forceinline__ unsigned short f2bu(float f) {
  union { __hip_bfloat16 h; unsigned short u; } cv;
  cv.h = __float2bfloat16(f);
  return cv.u;
}

// ---------------- K0: dtype detector (bf16 vs f32 inputs) --------------------
__global__ void detect_kernel(const void* __restrict__ x, int* __restrict__ flag) {
  __shared__ int cnt;
  if (threadIdx.x == 0) cnt = 0;
  __syncthreads();
  const unsigned short* u = (const unsigned short*)x;
  int c = 0;
#pragma unroll
  for (int s = 0; s < 16; ++s) {
    unsigned short v = u[threadIdx.x + s * 256];
    int e = (v >> 7) & 0xFF;
    if (e >= 140) c++;
  }
  atomicAdd(&cnt, c);
  __syncthreads();
  if (threadIdx.x == 0) flag[0] = (cnt > 64) ? 1 : 0;  // 1 = f32 inputs
}

// ---------------- K1: canonicalize all inputs to fp32 ------------------------
struct CanonTab {
  const void* src[25];
  int n[25];
  int off[25];
};

__global__ __launch_bounds__(256) void convert_kernel(
    CanonTab tab, const int* __restrict__ flag, float* __restrict__ canon) {
  int inp = blockIdx.y;
  int idx = blockIdx.x * 256 + threadIdx.x;
  if (idx >= tab.n[inp]) return;
  float v;
  if (flag[0]) v = ((const float*)tab.src[inp])[idx];
  else         v = b2f(((const __hip_bfloat16*)tab.src[inp])[idx]);
  canon[tab.off[inp] + idx] = v;
}

// ---------------- K2: softmax / logp / self-dot / x transpose ----------------
__global__ __launch_bounds__(256) void prep_kernel(
    const float* __restrict__ x,
    float* __restrict__ xT, float* __restrict__ p,
    float* __restrict__ lp, float* __restrict__ sd) {
  int tid = blockIdx.x * 256 + threadIdx.x;
  if (tid >= Mrows) return;
  int b = tid / Nn, n = tid - b * Nn;
  float xv[12];
#pragma unroll
  for (int t = 0; t < 12; ++t)
    xv[t] = x[((size_t)(b * Tn + t)) * Nn + n];
  float mx = xv[0];
#pragma unroll
  for (int t = 1; t < 12; ++t) mx = fmaxf(mx, xv[t]);
  float e[12]; float Z = 0.f;
#pragma unroll
  for (int t = 0; t < 12; ++t) { e[t] = expf(xv[t] - mx); Z += e[t]; }
  float invZ = 1.f / Z;
  float sacc = 0.f;
  size_t base = (size_t)tid * 12;
#pragma unroll
  for (int t = 0; t < 12; ++t) {
    float pv = e[t] * invZ;
    float lv = logf(pv + 1e-10f);
    p[base + t] = pv;
    lp[base + t] = lv;
    xT[base + t] = xv[t];
    sacc += pv * lv;
  }
  sd[tid] = sacc;
}

// ---------------- K3: fused KL threshold + bidirectional aggregation ---------
// 4-way j-split for occupancy: 1536 blocks x 4 waves = 6 waves/SIMD.
// Per block: 32 i x 8 j-slots; per thread 48 j iterations. shfl_xor reduces
// the 8 j-slots; partials per split land in psf/psb/prs/pcs.
constexpr int JSPLIT = 4;
__global__ __launch_bounds__(256) void kl_kernel(
    const float* __restrict__ p, const float* __restrict__ lp,
    const float* __restrict__ xT, const float* __restrict__ sd,
    float* __restrict__ psf, float* __restrict__ psb,
    float* __restrict__ prs, float* __restrict__ pcs) {
  int blk = blockIdx.x;          // 0..1535
  int b  = blk / 192;
  int r  = blk % 192;
  int ic = r >> 2;               // 0..47
  int js = r & 3;                // 0..3
  int tid = threadIdx.x;
  int il = tid >> 3;             // 0..31
  int jsl = tid & 7;             // 0..7
  int i = ic * 32 + il;
  int gi = b * Nn + i;

  float pi[12] __attribute__((aligned(16)));
  float li[12] __attribute__((aligned(16)));
  {
    const float4* p4 = (const float4*)(p + (size_t)gi * 12);
    ((float4*)pi)[0] = p4[0]; ((float4*)pi)[1] = p4[1]; ((float4*)pi)[2] = p4[2];
    const float4* l4 = (const float4*)(lp + (size_t)gi * 12);
    ((float4*)li)[0] = l4[0]; ((float4*)li)[1] = l4[1]; ((float4*)li)[2] = l4[2];
  }
  float self_i = sd[gi];

  float sf[12], sb[12];
#pragma unroll
  for (int t = 0; t < 12; ++t) { sf[t] = 0.f; sb[t] = 0.f; }
  float rs = 0.f, cs = 0.f;

  const float* pb  = p  + (size_t)b * Nn * 12;
  const float* lb  = lp + (size_t)b * Nn * 12;
  const float* xb  = xT + (size_t)b * Nn * 12;
  const float* sdb = sd + b * Nn;

  int jbase = js * 384 + jsl;
  for (int jj = 0; jj < 48; ++jj) {
    int j = jbase + (jj << 3);
    float pj[12] __attribute__((aligned(16)));
    float lj[12] __attribute__((aligned(16)));
    float xj[12] __attribute__((aligned(16)));
    {
      const float4* a = (const float4*)(pb + (size_t)j * 12);
      ((float4*)pj)[0] = a[0]; ((float4*)pj)[1] = a[1]; ((float4*)pj)[2] = a[2];
      const float4* c4 = (const float4*)(lb + (size_t)j * 12);
      ((float4*)lj)[0] = c4[0]; ((float4*)lj)[1] = c4[1]; ((float4*)lj)[2] = c4[2];
      const float4* d4 = (const float4*)(xb + (size_t)j * 12);
      ((float4*)xj)[0] = d4[0]; ((float4*)xj)[1] = d4[1]; ((float4*)xj)[2] = d4[2];
    }
    float self_j = sdb[j];
    float da = 0.f, db = 0.f;
#pragma unroll
    for (int t = 0; t < 12; ++t) {
      da = fmaf(pi[t], lj[t], da);
      db = fmaf(pj[t], li[t], db);
    }
    float cf = ((self_i - da) < 0.5f) ? 1.f : 0.f;  // A[i,j]
    float cb = ((self_j - db) < 0.5f) ? 1.f : 0.f;  // A[j,i]
    rs += cf; cs += cb;
#pragma unroll
    for (int t = 0; t < 12; ++t) {
      sf[t] = fmaf(cf, xj[t], sf[t]);
      sb[t] = fmaf(cb, xj[t], sb[t]);
    }
  }

#pragma unroll
  for (int off = 1; off <= 4; off <<= 1) {
    rs += __shfl_xor(rs, off);
    cs += __shfl_xor(cs, off);
#pragma unroll
    for (int t = 0; t < 12; ++t) {
      sf[t] += __shfl_xor(sf[t], off);
      sb[t] += __shfl_xor(sb[t], off);
    }
  }

  if (jsl == 0) {
    size_t o = ((size_t)js * Mrows + gi) * 12;
#pragma unroll
    for (int t = 0; t < 12; ++t) { psf[o + t] = sf[t]; psb[o + t] = sb[t]; }
    prs[(size_t)js * Mrows + gi] = rs;
    pcs[(size_t)js * Mrows + gi] = cs;
  }
}

// ---------------- K4: reduce partials -> diffusion coefficient c -------------
__global__ __launch_bounds__(256) void fin_kernel(
    const float* __restrict__ psf, const float* __restrict__ psb,
    const float* __restrict__ prs, const float* __restrict__ pcs,
    float* __restrict__ cc) {
  int tid = blockIdx.x * 256 + threadIdx.x;
  if (tid >= Mrows) return;
  float sf[12], sb[12];
#pragma unroll
  for (int t = 0; t < 12; ++t) { sf[t] = 0.f; sb[t] = 0.f; }
  float rs = 0.f, cs = 0.f;
  for (int s = 0; s < JSPLIT; ++s) {
    size_t o = ((size_t)s * Mrows + tid) * 12;
#pragma unroll
    for (int t = 0; t < 12; ++t) { sf[t] += psf[o + t]; sb[t] += psb[o + t]; }
    rs += prs[(size_t)s * Mrows + tid];
    cs += pcs[(size_t)s * Mrows + tid];
  }
  float irs = 1.f / fmaxf(rs, 1e-6f);
  float ics = 1.f / fmaxf(cs, 1e-6f);
#pragma unroll
  for (int t = 0; t < 12; ++t)
    cc[(size_t)tid * 12 + t] = 3.0f * (0.3f * sf[t] * irs + 0.7f * sb[t] * ics);
}

// ---------------- K5: repack weights f32 -> bf16 MFMA B-frag order -----------
// Frag order: (chunk c0 of 32 k) x (col-tile ct of 16 n) x (lane l) x (j 0..7)
// value = W[c0*32 + (l>>4)*8 + j][ct*16 + (l&15)]; cols >= Nc padded w/ 0.
struct RepTab {
  const float* src[8];
  int K[8], Nc[8], NCT[8];
  int lb[9];   // cumulative lane bases, lb[8] = total
};

__global__ __launch_bounds__(256) void repack_kernel(RepTab tab, unsigned short* __restrict__ Wf) {
  int idx = blockIdx.x * 256 + threadIdx.x;
  if (idx >= tab.lb[8]) return;
  int mi = 0;
#pragma unroll
  for (int i = 1; i < 8; ++i) if (idx >= tab.lb[i]) mi = i;
  int li = idx - tab.lb[mi];
  int NCT = tab.NCT[mi], Nc = tab.Nc[mi];
  int per = NCT * 64;
  int c0 = li / per, rem = li - c0 * per;
  int ct = rem >> 6, l = rem & 63;
  int q = l >> 4, m = l & 15;
  int col = ct * 16 + m;
  const float* s = tab.src[mi];
  unsigned short* d = Wf + (size_t)idx * 8;
#pragma unroll
  for (int j = 0; j < 8; ++j) {
    int k = c0 * 32 + q * 8 + j;
    float v = (col < Nc) ? s[(size_t)k * Nc + col] : 0.f;
    d[j] = f2bu(v);
  }
}

// ---------------- MFMA MLP GEMM (no LDS) -------------------------------------
// Wave covers 16 rows; block 256 thr = 4 waves = 64 rows; blockIdx.y = col grp.
// AMODE 0: A from bf16 activation buffer (pitch AP). AMODE 1: z generated
// on the fly from xT/cc (f32) and W1/W2 (f32): relu(x*W1[h] + c*W2[h]).
template <int CTB, int K, int AMODE, int NF>
__device__ __forceinline__ void mfma_chain(
    f4 (&acc)[CTB], int arow, int q, int l, int ct0,
    const unsigned short* __restrict__ Abuf, int AP,
    const unsigned short* __restrict__ Wf,
    const float* __restrict__ zxT, const float* __restrict__ zc,
    const float* __restrict__ zW1, const float* __restrict__ zW2) {
  constexpr int NCH = K / 32;
#pragma unroll 2
  for (int c0 = 0; c0 < NCH; ++c0) {
    bf8 a;
    if (AMODE == 0) {
      a = *(const bf8*)(Abuf + (size_t)arow * AP + c0 * 32 + q * 8);
    } else {
      int kb = c0 * 32 + q * 8;
      int t = kb >> 6, h0 = kb & 63;
      float xv = zxT[arow * 12 + t];
      float cv = zc[arow * 12 + t];
      union { bf8 v; unsigned short u[8]; } au;
#pragma unroll
      for (int j = 0; j < 8; ++j) {
        float z = fmaxf(fmaf(xv, zW1[h0 + j], cv * zW2[h0 + j]), 0.f);
        au.u[j] = f2bu(z);
      }
      a = au.v;
    }
    const unsigned short* wb = Wf + (((size_t)c0 * NF + ct0) * 64 + l) * 8;
#pragma unroll
    for (int ct = 0; ct < CTB; ++ct) {
      bf8 bfr = *(const bf8*)(wb + (size_t)ct * 512);
      acc[ct] = __builtin_amdgcn_mfma_f32_16x16x32_bf16(a, bfr, acc[ct], 0, 0, 0);
    }
  }
}

// EPI 0: relu -> bf16 [M x OP]; EPI 1: BN -> bf16 [M x OP];
// EPI 2: BN -> transposed final out[b, col, n], col < 12, dtype per flag.
template <int CTB, int AM1, int K1, int AM2, int K2, int EPI, int NF>
__global__ __launch_bounds__(256) void mfma_mlp(
    const unsigned short* __restrict__ A1, int AP1, const unsigned short* __restrict__ Wf1,
    const unsigned short* __restrict__ A2, int AP2, const unsigned short* __restrict__ Wf2,
    const float* __restrict__ bias,
    const float* __restrict__ bng, const float* __restrict__ bnbe,
    const float* __restrict__ bnm, const float* __restrict__ bnv,
    const float* __restrict__ zxT, const float* __restrict__ zc,
    const float* __restrict__ zW1, const float* __restrict__ zW2,
    void* __restrict__ outp, int OP, const int* __restrict__ flag) {
  int tid = threadIdx.x;
  int w = tid >> 6, l = tid & 63;
  int q = l >> 4, m = l & 15;
  int rowbase = blockIdx.x * 64 + w * 16;
  int arow = rowbase + m;
  int ct0 = blockIdx.y * CTB;

  f4 acc[CTB];
#pragma unroll
  for (int ct = 0; ct < CTB; ++ct) acc[ct] = {0.f, 0.f, 0.f, 0.f};

  mfma_chain<CTB, K1, AM1, NF>(acc, arow, q, l, ct0, A1, AP1, Wf1, zxT, zc, zW1, zW2);
  if constexpr (K2 > 0)
    mfma_chain<CTB, K2, AM2, NF>(acc, arow, q, l, ct0, A2, AP2, Wf2, zxT, zc, zW1, zW2);

  int isf32 = (EPI == 2) ? flag[0] : 0;
#pragma unroll
  for (int ct = 0; ct < CTB; ++ct) {
    int col = (ct0 + ct) * 16 + m;
    bool valid = (EPI != 2) || (col < TOUT);
    float bz = valid ? bias[col] : 0.f;
    float scale = 1.f, shift = 0.f;
    if (EPI >= 1 && valid) {
      float g = bng[col], be = bnbe[col], mm = bnm[col], vv = bnv[col];
      scale = g / sqrtf(vv + 1e-5f);
      shift = be - mm * scale;
    }
#pragma unroll
    for (int r = 0; r < 4; ++r) {
      int row = rowbase + q * 4 + r;
      float val = acc[ct][r] + bz;
      if (EPI == 0) {
        ((unsigned short*)outp)[(size_t)row * OP + col] = f2bu(fmaxf(val, 0.f));
      } else if (EPI == 1) {
        ((unsigned short*)outp)[(size_t)row * OP + col] = f2bu(val * scale + shift);
      } else if (valid) {
        int bb = row / Nn, nn = row - bb * Nn;
        size_t oi = ((size_t)bb * TOUT + col) * Nn + nn;
        float ov = val * scale + shift;
        if (isf32) ((float*)outp)[oi] = ov;
        else       ((unsigned short*)outp)[oi] = f2bu(ov);
      }
    }
  }
}

// canonical fp32 layout offsets (relative to canon base), dict order
static const int kOff[25] = {
    0, 147456, 147520, 147584, 245888, 246016, 262400, 262528, 270720, 270784,
    319936, 320000, 320064, 320128, 320192, 328384, 328512, 344896, 345024,
    346560, 346572, 347340, 347352, 347364, 347376};
static const int kN[25] = {
    147456, 64, 64, 98304, 128, 16384, 128, 8192, 64, 49152,
    64, 64, 64, 64, 8192, 128, 16384, 128, 1536,
    12, 768, 12, 12, 12, 12};

}  // namespace

extern "C" void kernel_launch(void* const* d_in, const int* in_sizes, int n_in,
                              void* d_out, int out_size, void* d_ws, size_t ws_size,
                              hipStream_t stream) {
  float* f = (float*)d_ws;
  int* flag = (int*)d_ws;            // f[0..15]
  float* CB = f + 16;                // canonical fp32 inputs
  float* xT  = f + 347408;           // 147456
  float* p   = f + 494864;           // 147456
  float* lp  = f + 642320;           // 147456
  float* sd  = f + 789776;           // 12288
  float* cc  = f + 802064;           // 147456
  float* psf = f + 949520;           // 4*12288*12
  float* psb = f + 1539344;          // 4*12288*12
  float* prs = f + 2129168;          // 4*12288
  float* pcs = f + 2178320;          // 4*12288
  unsigned short* Wf   = (unsigned short*)(f + 2227472);  // 199680 bf16
  unsigned short* bufA = (unsigned short*)(f + 2327312);  // 12288x128 bf16
  unsigned short* bufB = (unsigned short*)(f + 3113744);  // 12288x128 bf16
  unsigned short* xe   = (unsigned short*)(f + 3900176);  // 12288x64 bf16

  CanonTab tab;
  for (int i = 0; i < 25; ++i) { tab.src[i] = d_in[i]; tab.n[i] = kN[i]; tab.off[i] = kOff[i]; }

  const float* cx   = CB + kOff[0];
  const float* cW1  = CB + kOff[1];
  const float* cW2  = CB + kOff[2];
  const float* cew1 = CB + kOff[3];
  const float* ceb1 = CB + kOff[4];
  const float* cew2 = CB + kOff[5];
  const float* ceb2 = CB + kOff[6];
  const float* cew3 = CB + kOff[7];
  const float* ceb3 = CB + kOff[8];
  const float* cepj = CB + kOff[9];
  const float* cebg = CB + kOff[10];
  const float* cebb = CB + kOff[11];
  const float* cebm = CB + kOff[12];
  const float* cebv = CB + kOff[13];
  const float* cdw1 = CB + kOff[14];
  const float* cdb1 = CB + kOff[15];
  const float* cdw2 = CB + kOff[16];
  const float* cdb2 = CB + kOff[17];
  const float* cdw3 = CB + kOff[18];
  const float* cdb3 = CB + kOff[19];
  const float* cdpj = CB + kOff[20];
  const float* cdbg = CB + kOff[21];
  const float* cdbb = CB + kOff[22];
  const float* cdbm = CB + kOff[23];
  const float* cdbv = CB + kOff[24];

  // weight frag regions (bf16 elem offsets into Wf)
  unsigned short* Wf_ew1 = Wf + 0;
  unsigned short* Wf_ew2 = Wf + 98304;
  unsigned short* Wf_ew3 = Wf + 114688;
  unsigned short* Wf_epj = Wf + 122880;
  unsigned short* Wf_dw1 = Wf + 172032;
  unsigned short* Wf_dw2 = Wf + 180224;
  unsigned short* Wf_dw3 = Wf + 196608;
  unsigned short* Wf_dpj = Wf + 198656;

  RepTab rt;
  const float* rsrc[8] = {cew1, cew2, cew3, cepj, cdw1, cdw2, cdw3, cdpj};
  const int rK[8]   = {768, 128, 128, 768, 64, 128, 128, 64};
  const int rNc[8]  = {128, 128, 64, 64, 128, 128, 12, 12};
  const int rNCT[8] = {8, 8, 4, 4, 8, 8, 1, 1};
  const int rlb[9]  = {0, 12288, 14336, 15360, 21504, 22528, 24576, 24832, 24960};
  for (int i = 0; i < 8; ++i) {
    rt.src[i] = rsrc[i]; rt.K[i] = rK[i]; rt.Nc[i] = rNc[i]; rt.NCT[i] = rNCT[i];
  }
  for (int i = 0; i < 9; ++i) rt.lb[i] = rlb[i];

  detect_kernel<<<1, 256, 0, stream>>>(d_in[0], flag);
  convert_kernel<<<dim3(576, 25), 256, 0, stream>>>(tab, flag, CB);
  repack_kernel<<<98, 256, 0, stream>>>(rt, Wf);
  prep_kernel<<<48, 256, 0, stream>>>(cx, xT, p, lp, sd);
  kl_kernel<<<1536, 256, 0, stream>>>(p, lp, xT, sd, psf, psb, prs, pcs);
  fin_kernel<<<48, 256, 0, stream>>>(psf, psb, prs, pcs, cc);

  // L1e: bufA = relu(z @ enc_w1 + b1)   (z on the fly, K=768, N=128)
  mfma_mlp<4, 1, 768, 0, 0, 0, 8><<<dim3(192, 2), 256, 0, stream>>>(
      nullptr, 0, Wf_ew1, nullptr, 0, nullptr, ceb1,
      nullptr, nullptr, nullptr, nullptr, xT, cc, cW1, cW2, bufA, 128, flag);
  // L2e: bufB = relu(bufA @ enc_w2 + b2)   (K=128, N=128)
  mfma_mlp<4, 0, 128, 0, 0, 0, 8><<<dim3(192, 2), 256, 0, stream>>>(
      bufA, 128, Wf_ew2, nullptr, 0, nullptr, ceb2,
      nullptr, nullptr, nullptr, nullptr, nullptr, nullptr, nullptr, nullptr, bufB, 128, flag);
  // L3e: xe = BN(bufB @ enc_w3 + b3 + z @ enc_proj)   (N=64)
  mfma_mlp<4, 0, 128, 1, 768, 1, 4><<<dim3(192, 1), 256, 0, stream>>>(
      bufB, 128, Wf_ew3, nullptr, 0, Wf_epj, ceb3,
      cebg, cebb, cebm, cebv, xT, cc, cW1, cW2, xe, 64, flag);
  // L1d: bufA = relu(xe @ dec_w1 + b1)   (K=64, N=128)
  mfma_mlp<4, 0, 64, 0, 0, 0, 8><<<dim3(192, 2), 256, 0, stream>>>(
      xe, 64, Wf_dw1, nullptr, 0, nullptr, cdb1,
      nullptr, nullptr, nullptr, nullptr, nullptr, nullptr, nullptr, nullptr, bufA, 128, flag);
  // L2d: bufB = relu(bufA @ dec_w2 + b2)   (K=128, N=128)
  mfma_mlp<4, 0, 128, 0, 0, 0, 8><<<dim3(192, 2), 256, 0, stream>>>(
      bufA, 128, Wf_dw2, nullptr, 0, nullptr, cdb2,
      nullptr, nullptr, nullptr, nullptr, nullptr, nullptr, nullptr, nullptr, bufB, 128, flag);
  // L3d: out[b,t,n] = BN(bufB @ dec_w3 + b3 + xe @ dec_proj)[b,n,t]  (N=12)
  mfma_mlp<1, 0, 128, 0, 64, 2, 1><<<dim3(192, 1), 256, 0, stream>>>(
      bufB, 128, Wf_dw3, xe, 64, Wf_dpj, cdb3,
      cdbg, cdbb, cdbm, cdbv, nullptr, nullptr, nullptr, nullptr, d_out, 0, flag);
}

// Round 5
// 173.285 us; speedup vs baseline: 2.4726x; 1.4892x over previous
//
#include <hip/hip_runtime.h>
#include <hip/hip_bf16.h>

// AdaBiD R4b (resubmit - R4 run died to container infra, not kernel fault).
// MFMA everywhere + aggressive fusion. MI355X gfx950.
// B=8, T=12, N=1536, H=64, TH=768, HID2=128, T_OUT=12.
//  K0 detect+smalls: dtype sniff -> flag; canonicalize ~1K small params to f32
//  K1 prep: softmax/logp/self-dot; split-bf16 frag arrays (hi/lo) for the
//           KL GEMM; X' (x^T + ones col) in bf16
//  K2 repack: enc/dec weights -> MFMA B-frag order (bf16)
//  K3 kl_mfma: flash-style: S1=P_i*L_j^T, S2=L_i*P_j^T via split-bf16 MFMA,
//           threshold in f32 C-regs, 0/1 mask -> LDS -> A-frag, agg MFMA
//           against X' (ones col gives degrees). 8-way j-split partials.
//  K4 fin: reduce partials -> c[i,t]
//  K5 fused_mlp: ALL 6 MLP layers in one kernel (rows are independent);
//           z once into LDS frags; C-layout->A-frag transposes in LDS.

namespace {

constexpr int Bn = 8, Nn = 1536, TOUT = 12;
constexpr int Mrows = Bn * Nn;   // 12288
constexpr int JS = 8;            // j-split in kl

typedef __attribute__((ext_vector_type(8))) short bf8;
typedef __attribute__((ext_vector_type(4))) float f4;
typedef unsigned short ush;

__device__ __forceinline__ float b2f(__hip_bfloat16 v) { return __bfloat162float(v); }
__device__ __forceinline__ ush f2bu(float f) {
  union { __hip_bfloat16 h; ush u; } c; c.h = __float2bfloat16(f); return c.u;
}
__device__ __forceinline__ float bu2f(ush u) {
  union { unsigned int i; float f; } c; c.i = ((unsigned)u) << 16; return c.f;
}
__device__ __forceinline__ float ldraw(const void* p, size_t i, int fl) {
  return fl ? ((const float*)p)[i] : b2f(((const __hip_bfloat16*)p)[i]);
}

// ---------------- K0: dtype detect + canonicalize small params ---------------
struct SmallTab { const void* src[16]; int n[16]; int off[16]; };

__global__ __launch_bounds__(256) void detect_small(
    const void* __restrict__ x, int* __restrict__ flag, SmallTab st,
    float* __restrict__ CS) {
  __shared__ int cnt; __shared__ int fls;
  if (threadIdx.x == 0) cnt = 0;
  __syncthreads();
  const ush* u = (const ush*)x;
  int c = 0;
#pragma unroll
  for (int s = 0; s < 16; ++s) {
    ush v = u[threadIdx.x + s * 256];
    if (((v >> 7) & 0xFF) >= 140) c++;
  }
  atomicAdd(&cnt, c);
  __syncthreads();
  if (threadIdx.x == 0) { fls = (cnt > 64) ? 1 : 0; flag[0] = fls; }
  __syncthreads();
  int fl = fls;
  for (int i = 0; i < 16; ++i)
    for (int e = threadIdx.x; e < st.n[i]; e += 256)
      CS[st.off[i] + e] = ldraw(st.src[i], e, fl);
}

// ---------------- K1: prep -------------------------------------------------
// Per row (b,n): softmax over T, logp, self-dot. Writes:
//  xT f32[row][12], sd f32, Xc bf16[b][16][Nn] (rows 0..11=x, 12=ones),
//  pA/lA bf16[row][32] = [hi(12) 0x4 | lo(12) 0x4]  (A-frag source, K=32)
//  phi16/plo16/lhi16/llo16 bf16[row][16] = [hi/lo(12), 0x4] (B-frag source)
__global__ __launch_bounds__(256) void prep_kernel(
    const void* __restrict__ xraw, const int* __restrict__ flag,
    float* __restrict__ xT, float* __restrict__ sd,
    ush* __restrict__ pA, ush* __restrict__ lA,
    ush* __restrict__ phi16, ush* __restrict__ plo16,
    ush* __restrict__ lhi16, ush* __restrict__ llo16,
    ush* __restrict__ Xc) {
  int tid = blockIdx.x * 256 + threadIdx.x;
  if (tid >= Mrows) return;
  int b = tid / Nn, n = tid - b * Nn;
  int fl = flag[0];
  float xv[12];
#pragma unroll
  for (int t = 0; t < 12; ++t)
    xv[t] = ldraw(xraw, (size_t)(b * 12 + t) * Nn + n, fl);
  float mx = xv[0];
#pragma unroll
  for (int t = 1; t < 12; ++t) mx = fmaxf(mx, xv[t]);
  float e[12], Z = 0.f;
#pragma unroll
  for (int t = 0; t < 12; ++t) { e[t] = expf(xv[t] - mx); Z += e[t]; }
  float invZ = 1.f / Z;
  float sacc = 0.f;
  ush pa[32], la[32], ph[16], pl[16], lh[16], ll[16];
#pragma unroll
  for (int k = 0; k < 32; ++k) { pa[k] = 0; la[k] = 0; }
#pragma unroll
  for (int k = 0; k < 16; ++k) { ph[k] = 0; pl[k] = 0; lh[k] = 0; ll[k] = 0; }
#pragma unroll
  for (int t = 0; t < 12; ++t) {
    float pv = e[t] * invZ;
    float lv = logf(pv + 1e-10f);
    sacc += pv * lv;
    xT[(size_t)tid * 12 + t] = xv[t];
    ush phv = f2bu(pv);  float plv = pv - bu2f(phv);
    ush lhv = f2bu(lv);  float llv = lv - bu2f(lhv);
    pa[t] = phv; pa[16 + t] = f2bu(plv);
    la[t] = lhv; la[16 + t] = f2bu(llv);
    ph[t] = phv; pl[t] = f2bu(plv);
    lh[t] = lhv; ll[t] = f2bu(llv);
    Xc[((size_t)(b * 16 + t)) * Nn + n] = f2bu(xv[t]);
  }
  Xc[((size_t)(b * 16 + 12)) * Nn + n] = 0x3F80;  // ones col
#pragma unroll
  for (int t = 13; t < 16; ++t) Xc[((size_t)(b * 16 + t)) * Nn + n] = 0;
  sd[tid] = sacc;
  {
    uint4* d = (uint4*)(pA + (size_t)tid * 32);
    const uint4* s = (const uint4*)pa;
    d[0] = s[0]; d[1] = s[1]; d[2] = s[2]; d[3] = s[3];
    uint4* d2 = (uint4*)(lA + (size_t)tid * 32);
    const uint4* s2 = (const uint4*)la;
    d2[0] = s2[0]; d2[1] = s2[1]; d2[2] = s2[2]; d2[3] = s2[3];
    ((uint4*)(phi16 + (size_t)tid * 16))[0] = ((const uint4*)ph)[0];
    ((uint4*)(phi16 + (size_t)tid * 16))[1] = ((const uint4*)ph)[1];
    ((uint4*)(plo16 + (size_t)tid * 16))[0] = ((const uint4*)pl)[0];
    ((uint4*)(plo16 + (size_t)tid * 16))[1] = ((const uint4*)pl)[1];
    ((uint4*)(lhi16 + (size_t)tid * 16))[0] = ((const uint4*)lh)[0];
    ((uint4*)(lhi16 + (size_t)tid * 16))[1] = ((const uint4*)lh)[1];
    ((uint4*)(llo16 + (size_t)tid * 16))[0] = ((const uint4*)ll)[0];
    ((uint4*)(llo16 + (size_t)tid * 16))[1] = ((const uint4*)ll)[1];
  }
}

// ---------------- K2: weight repack -> B-frag order --------------------------
struct RepTab { const void* src[8]; int Nc[8]; int NCT[8]; int lb[9]; };

__global__ __launch_bounds__(256) void repack_kernel(
    RepTab tab, const int* __restrict__ flag, ush* __restrict__ Wf) {
  int idx = blockIdx.x * 256 + threadIdx.x;
  if (idx >= tab.lb[8]) return;
  int fl = flag[0];
  int mi = 0;
#pragma unroll
  for (int i = 1; i < 8; ++i) if (idx >= tab.lb[i]) mi = i;
  int li = idx - tab.lb[mi];
  int NCT = tab.NCT[mi], Nc = tab.Nc[mi];
  int per = NCT * 64;
  int c0 = li / per, rem = li - c0 * per;
  int ct = rem >> 6, l = rem & 63;
  int q = l >> 4, m = l & 15;
  int col = ct * 16 + m;
  ush* d = Wf + (size_t)idx * 8;
#pragma unroll
  for (int j = 0; j < 8; ++j) {
    int k = c0 * 32 + q * 8 + j;
    d[j] = (col < Nc) ? f2bu(ldraw(tab.src[mi], (size_t)k * Nc + col, fl)) : 0;
  }
}

// ---------------- K3: kl via MFMA (flash-style) ------------------------------
// Block 256 = 4 waves; wave owns a 16-row i-tile, loops 12 j-tiles of split js.
// S1 = (phi|plo)x(lhi|lhi) + (phi|0)x(llo|llo)   [= p_i . lp_j, err ~1e-4]
// S2 = (lhi|llo)x(phi|phi) + (lhi|0)x(plo|plo)   [= lp_i . p_j]
// A1=(self_i-S1<.5), A2=(self_j-S2<.5)=A[j,i]; agg vs X' (col12=ones->deg).
__global__ __launch_bounds__(256) void kl_mfma(
    const ush* __restrict__ pA, const ush* __restrict__ lA,
    const ush* __restrict__ phi16, const ush* __restrict__ plo16,
    const ush* __restrict__ lhi16, const ush* __restrict__ llo16,
    const ush* __restrict__ Xc, const float* __restrict__ sd,
    float* __restrict__ psf, float* __restrict__ psb) {
  __shared__ ush T1[4][512], T2[4][512];
  int tid = threadIdx.x, w = tid >> 6, l = tid & 63, q = l >> 4, n = l & 15;
  int blk = blockIdx.x;
  int b = blk / 192, rem = blk % 192, ig = rem >> 3, js = rem & 7;
  int i0 = ig * 64 + w * 16;
  int rowb = b * Nn;

  if (q >= 2) {  // zero the k>=16 pad of the mask frags (read-only region)
    uint4 z4 = {0, 0, 0, 0};
    *(uint4*)(&T1[w][(size_t)l * 8]) = z4;
    *(uint4*)(&T2[w][(size_t)l * 8]) = z4;
  }

  bf8 z8 = {0, 0, 0, 0, 0, 0, 0, 0};
  bf8 aP = *(const bf8*)(pA + ((size_t)(rowb + i0 + n)) * 32 + q * 8);
  bf8 aL = *(const bf8*)(lA + ((size_t)(rowb + i0 + n)) * 32 + q * 8);
  bf8 aPh = (q < 2) ? aP : z8;
  bf8 aLh = (q < 2) ? aL : z8;
  float selfI[4];
#pragma unroll
  for (int r = 0; r < 4; ++r) selfI[r] = sd[rowb + i0 + q * 4 + r];

  f4 accF = {0.f, 0.f, 0.f, 0.f}, accB = {0.f, 0.f, 0.f, 0.f};

  for (int jt = 0; jt < 12; ++jt) {
    int jl = js * 192 + jt * 16;
    size_t bb = ((size_t)(rowb + jl + n)) * 16 + (q & 1) * 8;
    bf8 bLh = *(const bf8*)(lhi16 + bb);
    bf8 bLo = *(const bf8*)(llo16 + bb);
    bf8 bPh = *(const bf8*)(phi16 + bb);
    bf8 bPo = *(const bf8*)(plo16 + bb);
    float selfJ = sd[rowb + jl + n];

    f4 s1 = {0.f, 0.f, 0.f, 0.f}, s2 = {0.f, 0.f, 0.f, 0.f};
    s1 = __builtin_amdgcn_mfma_f32_16x16x32_bf16(aP, bLh, s1, 0, 0, 0);
    s1 = __builtin_amdgcn_mfma_f32_16x16x32_bf16(aPh, bLo, s1, 0, 0, 0);
    s2 = __builtin_amdgcn_mfma_f32_16x16x32_bf16(aL, bPh, s2, 0, 0, 0);
    s2 = __builtin_amdgcn_mfma_f32_16x16x32_bf16(aLh, bPo, s2, 0, 0, 0);

    int qk = n >> 3, kj = n & 7;
#pragma unroll
    for (int r = 0; r < 4; ++r) {
      int pos = (qk * 16 + q * 4 + r) * 8 + kj;
      T1[w][pos] = (selfI[r] - s1[r] < 0.5f) ? (ush)0x3F80 : (ush)0;
      T2[w][pos] = (selfJ - s2[r] < 0.5f) ? (ush)0x3F80 : (ush)0;
    }
    bf8 af1 = *(const bf8*)(&T1[w][(size_t)l * 8]);
    bf8 af2 = *(const bf8*)(&T2[w][(size_t)l * 8]);
    bf8 xf = (q < 2)
        ? *(const bf8*)(Xc + ((size_t)(b * 16 + n)) * Nn + jl + q * 8) : z8;
    accF = __builtin_amdgcn_mfma_f32_16x16x32_bf16(af1, xf, accF, 0, 0, 0);
    accB = __builtin_amdgcn_mfma_f32_16x16x32_bf16(af2, xf, accB, 0, 0, 0);
  }
#pragma unroll
  for (int r = 0; r < 4; ++r) {
    size_t o = ((size_t)js * Mrows + rowb + i0 + q * 4 + r) * 16 + n;
    psf[o] = accF[r];
    psb[o] = accB[r];
  }
}

// ---------------- K4: reduce partials -> c -----------------------------------
__global__ __launch_bounds__(256) void fin_kernel(
    const float* __restrict__ psf, const float* __restrict__ psb,
    float* __restrict__ cc) {
  int tid = blockIdx.x * 256 + threadIdx.x;
  if (tid >= Mrows) return;
  float sf[16], sb[16];
#pragma unroll
  for (int t = 0; t < 16; ++t) { sf[t] = 0.f; sb[t] = 0.f; }
  for (int s = 0; s < JS; ++s) {
    const float4* a = (const float4*)(psf + ((size_t)s * Mrows + tid) * 16);
    const float4* c4 = (const float4*)(psb + ((size_t)s * Mrows + tid) * 16);
#pragma unroll
    for (int v = 0; v < 4; ++v) {
      float4 av = a[v], cv = c4[v];
      sf[v * 4 + 0] += av.x; sf[v * 4 + 1] += av.y; sf[v * 4 + 2] += av.z; sf[v * 4 + 3] += av.w;
      sb[v * 4 + 0] += cv.x; sb[v * 4 + 1] += cv.y; sb[v * 4 + 2] += cv.z; sb[v * 4 + 3] += cv.w;
    }
  }
  float irs = 1.f / fmaxf(sf[12], 1e-6f);
  float ics = 1.f / fmaxf(sb[12], 1e-6f);
#pragma unroll
  for (int t = 0; t < 12; ++t)
    cc[(size_t)tid * 12 + t] = 3.0f * (0.3f * sf[t] * irs + 0.7f * sb[t] * ics);
}

// ---------------- K5: fully fused MLP (6 layers, 1 wave = 16 rows) -----------
// LDS frag layout, lane-major: slot(c0, l) = (c0*64 + l)*8, holding elems
// A[m=l&15][k=(l>>4)*8 .. +7] -> conflict-free bf8 reads at own lane slot.
__global__ __launch_bounds__(64) void fused_mlp(
    const float* __restrict__ xT, const float* __restrict__ cc,
    const float* __restrict__ CS, const ush* __restrict__ Wf,
    const int* __restrict__ flag, void* __restrict__ outp) {
  __shared__ ush zf[24 * 512];   // z frags, K=768
  __shared__ ush hf[4 * 512];    // h1 / g1 frags, K=128
  __shared__ ush hg[4 * 512];    // h2 / g2 frags, K=128
  __shared__ ush xf[2 * 512];    // xe frags, K=64
  int l = threadIdx.x, q = l >> 4, n = l & 15;
  int r0 = blockIdx.x * 16;
  const float* W1c = CS; const float* W2c = CS + 64;

  // --- phase Z: z = relu(x*W1 + c*W2) once, into frag LDS -----------------
  for (int pp = 0; pp < 6; ++pp) {
    int pair = pp * 64 + l;          // 384 = 24 c0 x 16 rows
    int c0 = pair >> 4, mr = pair & 15;
    int grow = r0 + mr;
    int t = c0 >> 1, h0 = (c0 & 1) * 32;
    float xv = xT[(size_t)grow * 12 + t];
    float cv = cc[(size_t)grow * 12 + t];
#pragma unroll
    for (int s = 0; s < 4; ++s) {
      union { ush u[8]; uint4 v; } pk;
#pragma unroll
      for (int j = 0; j < 8; ++j) {
        int h = h0 + s * 8 + j;
        pk.u[j] = f2bu(fmaxf(fmaf(xv, W1c[h], cv * W2c[h]), 0.f));
      }
      *(uint4*)(&zf[(size_t)(c0 * 64 + s * 16 + mr) * 8]) = pk.v;
    }
  }
  __syncthreads();

  // --- L1e: h1 = relu(z @ ew1 + b1), N=128 --------------------------------
  f4 acc[8];
#pragma unroll
  for (int ct = 0; ct < 8; ++ct) acc[ct] = {0.f, 0.f, 0.f, 0.f};
  for (int c0 = 0; c0 < 24; ++c0) {
    bf8 a = *(const bf8*)(&zf[(size_t)(c0 * 64 + l) * 8]);
    const ush* wb = Wf + ((size_t)(c0 * 8) * 64 + l) * 8;   // ew1 @ 0, NF=8
#pragma unroll
    for (int ct = 0; ct < 8; ++ct) {
      bf8 bfr = *(const bf8*)(wb + (size_t)ct * 512);
      acc[ct] = __builtin_amdgcn_mfma_f32_16x16x32_bf16(a, bfr, acc[ct], 0, 0, 0);
    }
  }
#pragma unroll
  for (int ct = 0; ct < 8; ++ct) {
    int col = ct * 16 + n;
    float bz = CS[128 + col];
#pragma unroll
    for (int r = 0; r < 4; ++r) {
      int pos = ((ct >> 1) * 64 + ((ct & 1) * 2 + (n >> 3)) * 16 + q * 4 + r) * 8 + (n & 7);
      hf[pos] = f2bu(fmaxf(acc[ct][r] + bz, 0.f));
    }
  }
  __syncthreads();

  // --- L2e: h2 = relu(h1 @ ew2 + b2) --------------------------------------
#pragma unroll
  for (int ct = 0; ct < 8; ++ct) acc[ct] = {0.f, 0.f, 0.f, 0.f};
  for (int c0 = 0; c0 < 4; ++c0) {
    bf8 a = *(const bf8*)(&hf[(size_t)(c0 * 64 + l) * 8]);
    const ush* wb = Wf + 98304 + ((size_t)(c0 * 8) * 64 + l) * 8;
#pragma unroll
    for (int ct = 0; ct < 8; ++ct) {
      bf8 bfr = *(const bf8*)(wb + (size_t)ct * 512);
      acc[ct] = __builtin_amdgcn_mfma_f32_16x16x32_bf16(a, bfr, acc[ct], 0, 0, 0);
    }
  }
#pragma unroll
  for (int ct = 0; ct < 8; ++ct) {
    int col = ct * 16 + n;
    float bz = CS[256 + col];
#pragma unroll
    for (int r = 0; r < 4; ++r) {
      int pos = ((ct >> 1) * 64 + ((ct & 1) * 2 + (n >> 3)) * 16 + q * 4 + r) * 8 + (n & 7);
      hg[pos] = f2bu(fmaxf(acc[ct][r] + bz, 0.f));
    }
  }
  __syncthreads();

  // --- L3e: xe = BN(h2 @ ew3 + b3 + z @ eproj), N=64 ----------------------
  f4 a3[4];
#pragma unroll
  for (int ct = 0; ct < 4; ++ct) a3[ct] = {0.f, 0.f, 0.f, 0.f};
  for (int c0 = 0; c0 < 4; ++c0) {
    bf8 a = *(const bf8*)(&hg[(size_t)(c0 * 64 + l) * 8]);
    const ush* wb = Wf + 114688 + ((size_t)(c0 * 4) * 64 + l) * 8;   // ew3, NF=4
#pragma unroll
    for (int ct = 0; ct < 4; ++ct) {
      bf8 bfr = *(const bf8*)(wb + (size_t)ct * 512);
      a3[ct] = __builtin_amdgcn_mfma_f32_16x16x32_bf16(a, bfr, a3[ct], 0, 0, 0);
    }
  }
  for (int c0 = 0; c0 < 24; ++c0) {
    bf8 a = *(const bf8*)(&zf[(size_t)(c0 * 64 + l) * 8]);
    const ush* wb = Wf + 122880 + ((size_t)(c0 * 4) * 64 + l) * 8;   // eproj, NF=4
#pragma unroll
    for (int ct = 0; ct < 4; ++ct) {
      bf8 bfr = *(const bf8*)(wb + (size_t)ct * 512);
      a3[ct] = __builtin_amdgcn_mfma_f32_16x16x32_bf16(a, bfr, a3[ct], 0, 0, 0);
    }
  }
#pragma unroll
  for (int ct = 0; ct < 4; ++ct) {
    int col = ct * 16 + n;
    float g = CS[448 + col], be = CS[512 + col], mm = CS[576 + col], vv = CS[640 + col];
    float sc = g / sqrtf(vv + 1e-5f);
    float sh = be - mm * sc;
    float bz = CS[384 + col];
#pragma unroll
    for (int r = 0; r < 4; ++r) {
      int pos = ((ct >> 1) * 64 + ((ct & 1) * 2 + (n >> 3)) * 16 + q * 4 + r) * 8 + (n & 7);
      xf[pos] = f2bu((a3[ct][r] + bz) * sc + sh);
    }
  }
  __syncthreads();

  // --- L1d: g1 = relu(xe @ dw1 + b1), K=64 --------------------------------
#pragma unroll
  for (int ct = 0; ct < 8; ++ct) acc[ct] = {0.f, 0.f, 0.f, 0.f};
  for (int c0 = 0; c0 < 2; ++c0) {
    bf8 a = *(const bf8*)(&xf[(size_t)(c0 * 64 + l) * 8]);
    const ush* wb = Wf + 172032 + ((size_t)(c0 * 8) * 64 + l) * 8;   // dw1, NF=8
#pragma unroll
    for (int ct = 0; ct < 8; ++ct) {
      bf8 bfr = *(const bf8*)(wb + (size_t)ct * 512);
      acc[ct] = __builtin_amdgcn_mfma_f32_16x16x32_bf16(a, bfr, acc[ct], 0, 0, 0);
    }
  }
#pragma unroll
  for (int ct = 0; ct < 8; ++ct) {
    int col = ct * 16 + n;
    float bz = CS[704 + col];
#pragma unroll
    for (int r = 0; r < 4; ++r) {
      int pos = ((ct >> 1) * 64 + ((ct & 1) * 2 + (n >> 3)) * 16 + q * 4 + r) * 8 + (n & 7);
      hf[pos] = f2bu(fmaxf(acc[ct][r] + bz, 0.f));
    }
  }
  __syncthreads();

  // --- L2d: g2 = relu(g1 @ dw2 + b2) --------------------------------------
#pragma unroll
  for (int ct = 0; ct < 8; ++ct) acc[ct] = {0.f, 0.f, 0.f, 0.f};
  for (int c0 = 0; c0 < 4; ++c0) {
    bf8 a = *(const bf8*)(&hf[(size_t)(c0 * 64 + l) * 8]);
    const ush* wb = Wf + 180224 + ((size_t)(c0 * 8) * 64 + l) * 8;   // dw2, NF=8
#pragma unroll
    for (int ct = 0; ct < 8; ++ct) {
      bf8 bfr = *(const bf8*)(wb + (size_t)ct * 512);
      acc[ct] = __builtin_amdgcn_mfma_f32_16x16x32_bf16(a, bfr, acc[ct], 0, 0, 0);
    }
  }
#pragma unroll
  for (int ct = 0; ct < 8; ++ct) {
    int col = ct * 16 + n;
    float bz = CS[832 + col];
#pragma unroll
    for (int r = 0; r < 4; ++r) {
      int pos = ((ct >> 1) * 64 + ((ct & 1) * 2 + (n >> 3)) * 16 + q * 4 + r) * 8 + (n & 7);
      hg[pos] = f2bu(fmaxf(acc[ct][r] + bz, 0.f));
    }
  }
  __syncthreads();

  // --- L3d: out = BN(g2 @ dw3 + b3 + xe @ dproj), N=12, transposed store ---
  f4 ao = {0.f, 0.f, 0.f, 0.f};
  for (int c0 = 0; c0 < 4; ++c0) {
    bf8 a = *(const bf8*)(&hg[(size_t)(c0 * 64 + l) * 8]);
    bf8 bfr = *(const bf8*)(Wf + 196608 + ((size_t)c0 * 64 + l) * 8);  // dw3, NF=1
    ao = __builtin_amdgcn_mfma_f32_16x16x32_bf16(a, bfr, ao, 0, 0, 0);
  }
  for (int c0 = 0; c0 < 2; ++c0) {
    bf8 a = *(const bf8*)(&xf[(size_t)(c0 * 64 + l) * 8]);
    bf8 bfr = *(const bf8*)(Wf + 198656 + ((size_t)c0 * 64 + l) * 8);  // dproj
    ao = __builtin_amdgcn_mfma_f32_16x16x32_bf16(a, bfr, ao, 0, 0, 0);
  }
  int fl = flag[0];
  if (n < 12) {
    float bz = CS[960 + n];
    float g = CS[972 + n], be = CS[984 + n], mm = CS[996 + n], vv = CS[1008 + n];
    float sc = g / sqrtf(vv + 1e-5f);
    float sh = be - mm * sc;
#pragma unroll
    for (int r = 0; r < 4; ++r) {
      int row = r0 + q * 4 + r;
      int bb = row / Nn, nn = row - bb * Nn;
      size_t oi = ((size_t)bb * TOUT + n) * Nn + nn;
      float ov = (ao[r] + bz) * sc + sh;
      if (fl) ((float*)outp)[oi] = ov;
      else    ((ush*)outp)[oi] = f2bu(ov);
    }
  }
}

}  // namespace

extern "C" void kernel_launch(void* const* d_in, const int* in_sizes, int n_in,
                              void* d_out, int out_size, void* d_ws, size_t ws_size,
                              hipStream_t stream) {
  float* f = (float*)d_ws;
  int* flag = (int*)d_ws;                 // f[0..15]
  float* CS  = f + 16;                    // 1020 small params (f32)
  float* xT  = f + 1040;                  // 147456
  float* cc  = f + 148496;                // 147456
  float* sd  = f + 295952;                // 12288
  float* psf = f + 308240;                // 8*12288*16 = 1572864
  float* psb = f + 1881104;               // 1572864
  ush* U = (ush*)(f + 3453968);
  ush* pA    = U;                         // 12288*32
  ush* lA    = U + 393216;
  ush* phi16 = U + 786432;                // 12288*16
  ush* plo16 = U + 983040;
  ush* lhi16 = U + 1179648;
  ush* llo16 = U + 1376256;
  ush* Xc    = U + 1572864;               // 8*16*1536
  ush* Wf    = U + 1769472;               // 199680

  SmallTab st;
  {
    const int idxs[16] = {1, 2, 4, 6, 8, 10, 11, 12, 13, 15, 17, 19, 21, 22, 23, 24};
    const int ns[16]   = {64, 64, 128, 128, 64, 64, 64, 64, 64, 128, 128, 12, 12, 12, 12, 12};
    int off = 0;
    for (int i = 0; i < 16; ++i) {
      st.src[i] = d_in[idxs[i]]; st.n[i] = ns[i]; st.off[i] = off; off += ns[i];
    }
  }
  RepTab rt;
  {
    const int idxs[8]  = {3, 5, 7, 9, 14, 16, 18, 20};
    const int rNc[8]   = {128, 128, 64, 64, 128, 128, 12, 12};
    const int rNCT[8]  = {8, 8, 4, 4, 8, 8, 1, 1};
    const int rlb[9]   = {0, 12288, 14336, 15360, 21504, 22528, 24576, 24832, 24960};
    for (int i = 0; i < 8; ++i) {
      rt.src[i] = d_in[idxs[i]]; rt.Nc[i] = rNc[i]; rt.NCT[i] = rNCT[i];
    }
    for (int i = 0; i < 9; ++i) rt.lb[i] = rlb[i];
  }

  detect_small<<<1, 256, 0, stream>>>(d_in[0], flag, st, CS);
  prep_kernel<<<48, 256, 0, stream>>>(d_in[0], flag, xT, sd, pA, lA,
                                      phi16, plo16, lhi16, llo16, Xc);
  repack_kernel<<<98, 256, 0, stream>>>(rt, flag, Wf);
  kl_mfma<<<1536, 256, 0, stream>>>(pA, lA, phi16, plo16, lhi16, llo16,
                                    Xc, sd, psf, psb);
  fin_kernel<<<48, 256, 0, stream>>>(psf, psb, cc);
  fused_mlp<<<768, 64, 0, stream>>>(xT, cc, CS, Wf, flag, d_out);
}

// Round 6
// 155.597 us; speedup vs baseline: 2.7537x; 1.1137x over previous
//
#include <hip/hip_runtime.h>
#include <hip/hip_bf16.h>

// AdaBiD R6: 3-kernel pipeline. MI355X gfx950.
// B=8, T=12, N=1536, H=64, TH=768, HID2=128, T_OUT=12.
//  K1 prep_all: role by blockIdx: [0,48) softmax/logp/self-dot + frag arrays,
//               [48,146) weight repack -> B-frag order, 146 small params + flag.
//               Each block self-detects input dtype (bf16 vs f32) from x bits.
//  K2 kl_mfma:  flash-style KL threshold + bidirectional aggregation via
//               split-bf16 MFMA; 8-way j-split partials (unchanged from R5).
//  K3 fused_mlp: per 16-row tile: reduce kl partials -> c in LDS, then all 6
//               MLP layers; 4 waves column-split each layer (3 waves/SIMD),
//               z regenerated in registers (no 24KB LDS buffer), barriers
//               between layers, K-split + LDS reduce for the N=12 tail.

namespace {

constexpr int Bn = 8, Nn = 1536, TOUT = 12;
constexpr int Mrows = Bn * Nn;   // 12288
constexpr int JS = 8;            // j-split in kl

typedef __attribute__((ext_vector_type(8))) short bf8;
typedef __attribute__((ext_vector_type(4))) float f4;
typedef unsigned short ush;

__device__ __forceinline__ float b2f(__hip_bfloat16 v) { return __bfloat162float(v); }
__device__ __forceinline__ ush f2bu(float f) {
  union { __hip_bfloat16 h; ush u; } c; c.h = __float2bfloat16(f); return c.u;
}
__device__ __forceinline__ float bu2f(ush u) {
  union { unsigned int i; float f; } c; c.i = ((unsigned)u) << 16; return c.f;
}
__device__ __forceinline__ float ldraw(const void* p, size_t i, int fl) {
  return fl ? ((const float*)p)[i] : b2f(((const __hip_bfloat16*)p)[i]);
}

// block-local dtype sniff: bf16 N(0,1) never has exp-field >= 140; f32 read
// as ushorts has ~45% of low-halves >= 140.  4096 samples.
__device__ __forceinline__ int detect_fl(const void* x, int tid) {
  __shared__ int cnt;
  if (tid == 0) cnt = 0;
  __syncthreads();
  const ush* u = (const ush*)x;
  int c = 0;
#pragma unroll
  for (int s = 0; s < 16; ++s) {
    ush v = u[tid + s * 256];
    if (((v >> 7) & 0xFF) >= 140) c++;
  }
  atomicAdd(&cnt, c);
  __syncthreads();
  return (cnt > 64) ? 1 : 0;
}

struct SmallTab { const void* src[16]; int n[16]; int off[16]; };
struct RepTab { const void* src[8]; int Nc[8]; int NCT[8]; int lb[9]; };

// ---------------- K1: prep + repack + smalls ---------------------------------
__global__ __launch_bounds__(256) void prep_all(
    const void* __restrict__ xraw, SmallTab st, RepTab rt,
    int* __restrict__ flag, float* __restrict__ CS,
    float* __restrict__ xT, float* __restrict__ sd,
    ush* __restrict__ pA, ush* __restrict__ lA,
    ush* __restrict__ phi16, ush* __restrict__ plo16,
    ush* __restrict__ lhi16, ush* __restrict__ llo16,
    ush* __restrict__ Xc, ush* __restrict__ Wf) {
  int tid = threadIdx.x;
  int fl = detect_fl(xraw, tid);
  int blk = blockIdx.x;

  if (blk < 48) {
    // ---- prep role: one thread per (b,n) row ----
    int row = blk * 256 + tid;
    int b = row / Nn, n = row - b * Nn;
    float xv[12];
#pragma unroll
    for (int t = 0; t < 12; ++t)
      xv[t] = ldraw(xraw, (size_t)(b * 12 + t) * Nn + n, fl);
    float mx = xv[0];
#pragma unroll
    for (int t = 1; t < 12; ++t) mx = fmaxf(mx, xv[t]);
    float e[12], Z = 0.f;
#pragma unroll
    for (int t = 0; t < 12; ++t) { e[t] = expf(xv[t] - mx); Z += e[t]; }
    float invZ = 1.f / Z;
    float sacc = 0.f;
    ush pa[32], la[32], ph[16], pl[16], lh[16], ll[16];
#pragma unroll
    for (int k = 0; k < 32; ++k) { pa[k] = 0; la[k] = 0; }
#pragma unroll
    for (int k = 0; k < 16; ++k) { ph[k] = 0; pl[k] = 0; lh[k] = 0; ll[k] = 0; }
#pragma unroll
    for (int t = 0; t < 12; ++t) {
      float pv = e[t] * invZ;
      float lv = logf(pv + 1e-10f);
      sacc += pv * lv;
      xT[(size_t)row * 12 + t] = xv[t];
      ush phv = f2bu(pv);  float plv = pv - bu2f(phv);
      ush lhv = f2bu(lv);  float llv = lv - bu2f(lhv);
      pa[t] = phv; pa[16 + t] = f2bu(plv);
      la[t] = lhv; la[16 + t] = f2bu(llv);
      ph[t] = phv; pl[t] = f2bu(plv);
      lh[t] = lhv; ll[t] = f2bu(llv);
      Xc[((size_t)(b * 16 + t)) * Nn + n] = f2bu(xv[t]);
    }
    Xc[((size_t)(b * 16 + 12)) * Nn + n] = 0x3F80;  // ones col -> degrees
#pragma unroll
    for (int t = 13; t < 16; ++t) Xc[((size_t)(b * 16 + t)) * Nn + n] = 0;
    sd[row] = sacc;
    {
      uint4* d = (uint4*)(pA + (size_t)row * 32);
      const uint4* s = (const uint4*)pa;
      d[0] = s[0]; d[1] = s[1]; d[2] = s[2]; d[3] = s[3];
      uint4* d2 = (uint4*)(lA + (size_t)row * 32);
      const uint4* s2 = (const uint4*)la;
      d2[0] = s2[0]; d2[1] = s2[1]; d2[2] = s2[2]; d2[3] = s2[3];
      ((uint4*)(phi16 + (size_t)row * 16))[0] = ((const uint4*)ph)[0];
      ((uint4*)(phi16 + (size_t)row * 16))[1] = ((const uint4*)ph)[1];
      ((uint4*)(plo16 + (size_t)row * 16))[0] = ((const uint4*)pl)[0];
      ((uint4*)(plo16 + (size_t)row * 16))[1] = ((const uint4*)pl)[1];
      ((uint4*)(lhi16 + (size_t)row * 16))[0] = ((const uint4*)lh)[0];
      ((uint4*)(lhi16 + (size_t)row * 16))[1] = ((const uint4*)lh)[1];
      ((uint4*)(llo16 + (size_t)row * 16))[0] = ((const uint4*)ll)[0];
      ((uint4*)(llo16 + (size_t)row * 16))[1] = ((const uint4*)ll)[1];
    }
  } else if (blk < 146) {
    // ---- repack role: weights -> MFMA B-frag order ----
    int idx = (blk - 48) * 256 + tid;
    if (idx >= rt.lb[8]) return;
    int mi = 0;
#pragma unroll
    for (int i = 1; i < 8; ++i) if (idx >= rt.lb[i]) mi = i;
    int li = idx - rt.lb[mi];
    int NCT = rt.NCT[mi], Nc = rt.Nc[mi];
    int per = NCT * 64;
    int c0 = li / per, rem = li - c0 * per;
    int ct = rem >> 6, l = rem & 63;
    int q = l >> 4, m = l & 15;
    int col = ct * 16 + m;
    ush* d = Wf + (size_t)idx * 8;
#pragma unroll
    for (int j = 0; j < 8; ++j) {
      int k = c0 * 32 + q * 8 + j;
      d[j] = (col < Nc) ? f2bu(ldraw(rt.src[mi], (size_t)k * Nc + col, fl)) : 0;
    }
  } else {
    // ---- smalls role: canonicalize biases/BN params to f32 + publish flag ----
    for (int i = 0; i < 16; ++i)
      for (int e = tid; e < st.n[i]; e += 256)
        CS[st.off[i] + e] = ldraw(st.src[i], e, fl);
    if (tid == 0) flag[0] = fl;
  }
}

// ---------------- K2: kl via MFMA (flash-style) ------------------------------
// Block 256 = 4 waves; wave owns a 16-row i-tile, loops 12 j-tiles of split js.
// S1 = p_i . lp_j via split-bf16 (hi/lo), S2 = lp_i . p_j likewise.
// A1=(self_i-S1<.5)=A[i,j], A2=(self_j-S2<.5)=A[j,i]; aggregate both against
// X' (cols 0..11 = x, col 12 = ones -> row/col degrees). Wave-private LDS
// roundtrip converts the 0/1 mask from C-layout to A-frag layout.
__global__ __launch_bounds__(256) void kl_mfma(
    const ush* __restrict__ pA, const ush* __restrict__ lA,
    const ush* __restrict__ phi16, const ush* __restrict__ plo16,
    const ush* __restrict__ lhi16, const ush* __restrict__ llo16,
    const ush* __restrict__ Xc, const float* __restrict__ sd,
    float* __restrict__ psf, float* __restrict__ psb) {
  __shared__ ush T1[4][512], T2[4][512];
  int tid = threadIdx.x, w = tid >> 6, l = tid & 63, q = l >> 4, n = l & 15;
  int blk = blockIdx.x;
  int b = blk / 192, rem = blk % 192, ig = rem >> 3, js = rem & 7;
  int i0 = ig * 64 + w * 16;
  int rowb = b * Nn;

  if (q >= 2) {  // zero the k>=16 pad of the mask frags once
    uint4 z4 = {0, 0, 0, 0};
    *(uint4*)(&T1[w][(size_t)l * 8]) = z4;
    *(uint4*)(&T2[w][(size_t)l * 8]) = z4;
  }

  bf8 z8 = {0, 0, 0, 0, 0, 0, 0, 0};
  bf8 aP = *(const bf8*)(pA + ((size_t)(rowb + i0 + n)) * 32 + q * 8);
  bf8 aL = *(const bf8*)(lA + ((size_t)(rowb + i0 + n)) * 32 + q * 8);
  bf8 aPh = (q < 2) ? aP : z8;
  bf8 aLh = (q < 2) ? aL : z8;
  float selfI[4];
#pragma unroll
  for (int r = 0; r < 4; ++r) selfI[r] = sd[rowb + i0 + q * 4 + r];

  f4 accF = {0.f, 0.f, 0.f, 0.f}, accB = {0.f, 0.f, 0.f, 0.f};

  for (int jt = 0; jt < 12; ++jt) {
    int jl = js * 192 + jt * 16;
    size_t bb = ((size_t)(rowb + jl + n)) * 16 + (q & 1) * 8;
    bf8 bLh = *(const bf8*)(lhi16 + bb);
    bf8 bLo = *(const bf8*)(llo16 + bb);
    bf8 bPh = *(const bf8*)(phi16 + bb);
    bf8 bPo = *(const bf8*)(plo16 + bb);
    float selfJ = sd[rowb + jl + n];

    f4 s1 = {0.f, 0.f, 0.f, 0.f}, s2 = {0.f, 0.f, 0.f, 0.f};
    s1 = __builtin_amdgcn_mfma_f32_16x16x32_bf16(aP, bLh, s1, 0, 0, 0);
    s1 = __builtin_amdgcn_mfma_f32_16x16x32_bf16(aPh, bLo, s1, 0, 0, 0);
    s2 = __builtin_amdgcn_mfma_f32_16x16x32_bf16(aL, bPh, s2, 0, 0, 0);
    s2 = __builtin_amdgcn_mfma_f32_16x16x32_bf16(aLh, bPo, s2, 0, 0, 0);

    int qk = n >> 3, kj = n & 7;
#pragma unroll
    for (int r = 0; r < 4; ++r) {
      int pos = (qk * 16 + q * 4 + r) * 8 + kj;
      T1[w][pos] = (selfI[r] - s1[r] < 0.5f) ? (ush)0x3F80 : (ush)0;
      T2[w][pos] = (selfJ - s2[r] < 0.5f) ? (ush)0x3F80 : (ush)0;
    }
    bf8 af1 = *(const bf8*)(&T1[w][(size_t)l * 8]);
    bf8 af2 = *(const bf8*)(&T2[w][(size_t)l * 8]);
    bf8 xfr = (q < 2)
        ? *(const bf8*)(Xc + ((size_t)(b * 16 + n)) * Nn + jl + q * 8) : z8;
    accF = __builtin_amdgcn_mfma_f32_16x16x32_bf16(af1, xfr, accF, 0, 0, 0);
    accB = __builtin_amdgcn_mfma_f32_16x16x32_bf16(af2, xfr, accB, 0, 0, 0);
  }
#pragma unroll
  for (int r = 0; r < 4; ++r) {
    size_t o = ((size_t)js * Mrows + rowb + i0 + q * 4 + r) * 16 + n;
    psf[o] = accF[r];
    psb[o] = accB[r];
  }
}

// ---------------- K3: fused MLP, 4 waves / 16-row tile -----------------------
// LDS frag layout (lane-major): slot(c0, l)*8+j holds A[m=l&15][k=(l>>4)*8+j].
// Wave w handles col-tiles {2w,2w+1} for N=128 layers, {w} for N=64 layer,
// K-split for the N=12 tail. Barriers between layers.
__global__ __launch_bounds__(256) void fused_mlp(
    const float* __restrict__ xT,
    const float* __restrict__ psf, const float* __restrict__ psb,
    const float* __restrict__ CS, const ush* __restrict__ Wf,
    const int* __restrict__ flag, void* __restrict__ outp) {
  __shared__ float xs[16][12], ccs[16][12];
  __shared__ float sfs[16][16], sbs[16][16];
  __shared__ float ws1[64], ws2[64];
  __shared__ ush hf[2048], hg[2048], xf[1024];
  __shared__ f4 red[4][64];

  int tid = threadIdx.x, w = tid >> 6, l = tid & 63, q = l >> 4, n = l & 15;
  int r0 = blockIdx.x * 16;

  // --- init: xs, W1/W2, and kl-partial reduction -> sfs/sbs ----------------
  {
    int r = tid >> 4, t = tid & 15;
    float a = 0.f, b = 0.f;
#pragma unroll
    for (int js = 0; js < JS; ++js) {
      size_t o = ((size_t)js * Mrows + r0 + r) * 16 + t;
      a += psf[o];
      b += psb[o];
    }
    sfs[r][t] = a;
    sbs[r][t] = b;
    if (tid < 128) { if (tid < 64) ws1[tid] = CS[tid]; else ws2[tid - 64] = CS[tid]; }
    if (tid < 192) {
      int rr = tid / 12, tt = tid - rr * 12;
      xs[rr][tt] = xT[(size_t)(r0 + rr) * 12 + tt];
    }
  }
  __syncthreads();
  if (tid < 192) {
    int rr = tid / 12, tt = tid - rr * 12;
    float irs = 1.f / fmaxf(sfs[rr][12], 1e-6f);
    float ics = 1.f / fmaxf(sbs[rr][12], 1e-6f);
    ccs[rr][tt] = 3.0f * (0.3f * sfs[rr][tt] * irs + 0.7f * sbs[rr][tt] * ics);
  }
  __syncthreads();

  // z A-frag regen: row = r0+n, k = c0*32 + q*8 + j
  auto zregen = [&](int c0) -> bf8 {
    int t = c0 >> 1, h0 = (c0 & 1) * 32 + q * 8;
    float xv = xs[n][t], cv = ccs[n][t];
    union { bf8 v; ush u[8]; } au;
#pragma unroll
    for (int j = 0; j < 8; ++j)
      au.u[j] = f2bu(fmaxf(fmaf(xv, ws1[h0 + j], cv * ws2[h0 + j]), 0.f));
    return au.v;
  };
  // C-layout -> frag-slot store position for col-tile ct
  auto fpos = [&](int ct, int r) -> int {
    return ((ct >> 1) * 64 + ((ct & 1) * 2 + (n >> 3)) * 16 + q * 4 + r) * 8 + (n & 7);
  };

  // --- L1e: h1 = relu(z @ ew1 + b1), N=128, wave does ct = 2w, 2w+1 --------
  {
    f4 a0 = {0.f, 0.f, 0.f, 0.f}, a1 = {0.f, 0.f, 0.f, 0.f};
    for (int c0 = 0; c0 < 24; ++c0) {
      bf8 a = zregen(c0);
      const ush* wb = Wf + ((size_t)(c0 * 8 + 2 * w) * 64 + l) * 8;
      bf8 b0 = *(const bf8*)wb;
      bf8 b1 = *(const bf8*)(wb + 512);
      a0 = __builtin_amdgcn_mfma_f32_16x16x32_bf16(a, b0, a0, 0, 0, 0);
      a1 = __builtin_amdgcn_mfma_f32_16x16x32_bf16(a, b1, a1, 0, 0, 0);
    }
#pragma unroll
    for (int u2 = 0; u2 < 2; ++u2) {
      int ct = 2 * w + u2;
      f4 acc = u2 ? a1 : a0;
      float bz = CS[128 + ct * 16 + n];
#pragma unroll
      for (int r = 0; r < 4; ++r)
        hf[fpos(ct, r)] = f2bu(fmaxf(acc[r] + bz, 0.f));
    }
  }
  __syncthreads();

  // --- L2e: h2 = relu(h1 @ ew2 + b2), K=128 --------------------------------
  {
    f4 a0 = {0.f, 0.f, 0.f, 0.f}, a1 = {0.f, 0.f, 0.f, 0.f};
    for (int c0 = 0; c0 < 4; ++c0) {
      bf8 a = *(const bf8*)(&hf[(size_t)(c0 * 64 + l) * 8]);
      const ush* wb = Wf + 98304 + ((size_t)(c0 * 8 + 2 * w) * 64 + l) * 8;
      bf8 b0 = *(const bf8*)wb;
      bf8 b1 = *(const bf8*)(wb + 512);
      a0 = __builtin_amdgcn_mfma_f32_16x16x32_bf16(a, b0, a0, 0, 0, 0);
      a1 = __builtin_amdgcn_mfma_f32_16x16x32_bf16(a, b1, a1, 0, 0, 0);
    }
    __syncthreads();   // before overwriting hg? (hg unused yet) -- protect hf reads done
#pragma unroll
    for (int u2 = 0; u2 < 2; ++u2) {
      int ct = 2 * w + u2;
      f4 acc = u2 ? a1 : a0;
      float bz = CS[256 + ct * 16 + n];
#pragma unroll
      for (int r = 0; r < 4; ++r)
        hg[fpos(ct, r)] = f2bu(fmaxf(acc[r] + bz, 0.f));
    }
  }
  __syncthreads();

  // --- L3e: xe = BN(h2 @ ew3 + b3 + z @ eproj), N=64, wave does ct = w -----
  {
    f4 a3 = {0.f, 0.f, 0.f, 0.f};
    for (int c0 = 0; c0 < 4; ++c0) {
      bf8 a = *(const bf8*)(&hg[(size_t)(c0 * 64 + l) * 8]);
      bf8 b = *(const bf8*)(Wf + 114688 + ((size_t)(c0 * 4 + w) * 64 + l) * 8);
      a3 = __builtin_amdgcn_mfma_f32_16x16x32_bf16(a, b, a3, 0, 0, 0);
    }
    for (int c0 = 0; c0 < 24; ++c0) {
      bf8 a = zregen(c0);
      bf8 b = *(const bf8*)(Wf + 122880 + ((size_t)(c0 * 4 + w) * 64 + l) * 8);
      a3 = __builtin_amdgcn_mfma_f32_16x16x32_bf16(a, b, a3, 0, 0, 0);
    }
    int col = w * 16 + n;
    float g = CS[448 + col], be = CS[512 + col], mm = CS[576 + col], vv = CS[640 + col];
    float sc = g / sqrtf(vv + 1e-5f);
    float sh = be - mm * sc;
    float bz = CS[384 + col];
#pragma unroll
    for (int r = 0; r < 4; ++r)
      xf[fpos(w, r)] = f2bu((a3[r] + bz) * sc + sh);
  }
  __syncthreads();

  // --- L1d: g1 = relu(xe @ dw1 + b1), K=64, N=128 --------------------------
  {
    f4 a0 = {0.f, 0.f, 0.f, 0.f}, a1 = {0.f, 0.f, 0.f, 0.f};
    for (int c0 = 0; c0 < 2; ++c0) {
      bf8 a = *(const bf8*)(&xf[(size_t)(c0 * 64 + l) * 8]);
      const ush* wb = Wf + 172032 + ((size_t)(c0 * 8 + 2 * w) * 64 + l) * 8;
      bf8 b0 = *(const bf8*)wb;
      bf8 b1 = *(const bf8*)(wb + 512);
      a0 = __builtin_amdgcn_mfma_f32_16x16x32_bf16(a, b0, a0, 0, 0, 0);
      a1 = __builtin_amdgcn_mfma_f32_16x16x32_bf16(a, b1, a1, 0, 0, 0);
    }
    __syncthreads();   // hf is about to be overwritten; L2e reads of hf are long done
#pragma unroll
    for (int u2 = 0; u2 < 2; ++u2) {
      int ct = 2 * w + u2;
      f4 acc = u2 ? a1 : a0;
      float bz = CS[704 + ct * 16 + n];
#pragma unroll
      for (int r = 0; r < 4; ++r)
        hf[fpos(ct, r)] = f2bu(fmaxf(acc[r] + bz, 0.f));
    }
  }
  __syncthreads();

  // --- L2d: g2 = relu(g1 @ dw2 + b2), K=128 --------------------------------
  {
    f4 a0 = {0.f, 0.f, 0.f, 0.f}, a1 = {0.f, 0.f, 0.f, 0.f};
    for (int c0 = 0; c0 < 4; ++c0) {
      bf8 a = *(const bf8*)(&hf[(size_t)(c0 * 64 + l) * 8]);
      const ush* wb = Wf + 180224 + ((size_t)(c0 * 8 + 2 * w) * 64 + l) * 8;
      bf8 b0 = *(const bf8*)wb;
      bf8 b1 = *(const bf8*)(wb + 512);
      a0 = __builtin_amdgcn_mfma_f32_16x16x32_bf16(a, b0, a0, 0, 0, 0);
      a1 = __builtin_amdgcn_mfma_f32_16x16x32_bf16(a, b1, a1, 0, 0, 0);
    }
    __syncthreads();   // hg rewrite fence
#pragma unroll
    for (int u2 = 0; u2 < 2; ++u2) {
      int ct = 2 * w + u2;
      f4 acc = u2 ? a1 : a0;
      float bz = CS[832 + ct * 16 + n];
#pragma unroll
      for (int r = 0; r < 4; ++r)
        hg[fpos(ct, r)] = f2bu(fmaxf(acc[r] + bz, 0.f));
    }
  }
  __syncthreads();

  // --- L3d: out = BN(g2 @ dw3 + b3 + xe @ dproj), N=12; K-split 4 waves ----
  {
    f4 ao = {0.f, 0.f, 0.f, 0.f};
    {  // dw3 chunk c0 = w  (K=128 -> 4 chunks)
      bf8 a = *(const bf8*)(&hg[(size_t)(w * 64 + l) * 8]);
      bf8 b = *(const bf8*)(Wf + 196608 + ((size_t)w * 64 + l) * 8);
      ao = __builtin_amdgcn_mfma_f32_16x16x32_bf16(a, b, ao, 0, 0, 0);
    }
    if (w < 2) {  // dproj chunk c0 = w  (K=64 -> 2 chunks)
      bf8 a = *(const bf8*)(&xf[(size_t)(w * 64 + l) * 8]);
      bf8 b = *(const bf8*)(Wf + 198656 + ((size_t)w * 64 + l) * 8);
      ao = __builtin_amdgcn_mfma_f32_16x16x32_bf16(a, b, ao, 0, 0, 0);
    }
    red[w][l] = ao;
  }
  __syncthreads();
  if (w == 0) {
    f4 s = red[0][l] + red[1][l] + red[2][l] + red[3][l];
    int fl = flag[0];
    if (n < 12) {
      float bz = CS[960 + n];
      float g = CS[972 + n], be = CS[984 + n], mm = CS[996 + n], vv = CS[1008 + n];
      float sc = g / sqrtf(vv + 1e-5f);
      float sh = be - mm * sc;
#pragma unroll
      for (int r = 0; r < 4; ++r) {
        int row = r0 + q * 4 + r;
        int bb = row / Nn, nn = row - bb * Nn;
        size_t oi = ((size_t)bb * TOUT + n) * Nn + nn;
        float ov = (s[r] + bz) * sc + sh;
        if (fl) ((float*)outp)[oi] = ov;
        else    ((ush*)outp)[oi] = f2bu(ov);
      }
    }
  }
}

}  // namespace

extern "C" void kernel_launch(void* const* d_in, const int* in_sizes, int n_in,
                              void* d_out, int out_size, void* d_ws, size_t ws_size,
                              hipStream_t stream) {
  float* f = (float*)d_ws;
  int* flag = (int*)d_ws;                 // f[0..15]
  float* CS  = f + 16;                    // 1020 small params (f32)
  float* xT  = f + 1040;                  // 147456
  float* sd  = f + 148496;                // 12288
  float* psf = f + 160784;                // 8*12288*16 = 1572864
  float* psb = f + 1733648;               // 1572864
  ush* U = (ush*)(f + 3306512);
  ush* pA    = U;                         // 12288*32
  ush* lA    = U + 393216;
  ush* phi16 = U + 786432;                // 12288*16
  ush* plo16 = U + 983040;
  ush* lhi16 = U + 1179648;
  ush* llo16 = U + 1376256;
  ush* Xc    = U + 1572864;               // 8*16*1536
  ush* Wf    = U + 1769472;               // 199680

  SmallTab st;
  {
    const int idxs[16] = {1, 2, 4, 6, 8, 10, 11, 12, 13, 15, 17, 19, 21, 22, 23, 24};
    const int ns[16]   = {64, 64, 128, 128, 64, 64, 64, 64, 64, 128, 128, 12, 12, 12, 12, 12};
    int off = 0;
    for (int i = 0; i < 16; ++i) {
      st.src[i] = d_in[idxs[i]]; st.n[i] = ns[i]; st.off[i] = off; off += ns[i];
    }
  }
  RepTab rt;
  {
    const int idxs[8]  = {3, 5, 7, 9, 14, 16, 18, 20};
    const int rNc[8]   = {128, 128, 64, 64, 128, 128, 12, 12};
    const int rNCT[8]  = {8, 8, 4, 4, 8, 8, 1, 1};
    const int rlb[9]   = {0, 12288, 14336, 15360, 21504, 22528, 24576, 24832, 24960};
    for (int i = 0; i < 8; ++i) {
      rt.src[i] = d_in[idxs[i]]; rt.Nc[i] = rNc[i]; rt.NCT[i] = rNCT[i];
    }
    for (int i = 0; i < 9; ++i) rt.lb[i] = rlb[i];
  }

  prep_all<<<147, 256, 0, stream>>>(d_in[0], st, rt, flag, CS, xT, sd,
                                    pA, lA, phi16, plo16, lhi16, llo16, Xc, Wf);
  kl_mfma<<<1536, 256, 0, stream>>>(pA, lA, phi16, plo16, lhi16, llo16,
                                    Xc, sd, psf, psb);
  fused_mlp<<<768, 256, 0, stream>>>(xT, psf, psb, CS, Wf, flag, d_out);
}